// Round 1
// baseline (479.819 us; speedup 1.0000x reference)
//
#include <hip/hip_runtime.h>

#define NN 512
#define MROWS (NN*NN)        // 262144
#define LDK 136              // padded bf16 row stride (k-dim 128 + 8)

typedef __attribute__((ext_vector_type(8))) short short8;
typedef __attribute__((ext_vector_type(4))) float floatx4;

__device__ __forceinline__ unsigned short f2bf(float f) {
    union { float f; unsigned u; } x; x.f = f;
    unsigned r = x.u + 0x7fffu + ((x.u >> 16) & 1u);
    return (unsigned short)(r >> 16);
}

// ---------------- prep: convert Wb (512x128) and Wbo (128x512) to bf16 ----------------
__global__ void prep_kernel(const float* __restrict__ Wb, const float* __restrict__ Wbo,
                            unsigned short* __restrict__ wbf) {
    int i = blockIdx.x * 256 + threadIdx.x;      // grid 512 -> 131072 threads
    float v = (i < 65536) ? Wb[i] : Wbo[i - 65536];
    wbf[i] = f2bf(v);
}

// ---------------- projections: pq = q@Wq.T + bq, pk = k@Wk.T + bk ----------------
__global__ __launch_bounds__(256) void proj_kernel(
    const float* __restrict__ q, const float* __restrict__ k,
    const float* __restrict__ Wq, const float* __restrict__ bq,
    const float* __restrict__ Wk, const float* __restrict__ bk,
    float* __restrict__ pq, float* __restrict__ pk)
{
    __shared__ float xs[64];
    int b = blockIdx.x;
    int n = b & 511;
    int is_k = b >> 9;
    const float* x  = is_k ? k  : q;
    const float* W  = is_k ? Wk : Wq;
    const float* bi = is_k ? bk : bq;
    float* out      = is_k ? pk : pq;
    int tid = threadIdx.x;
    if (tid < 16)
        reinterpret_cast<float4*>(xs)[tid] = reinterpret_cast<const float4*>(x + n*64)[tid];
    __syncthreads();
    #pragma unroll
    for (int jj = 0; jj < 2; ++jj) {
        int j = jj*256 + tid;
        const float4* wr = reinterpret_cast<const float4*>(W + j*64);
        float acc = bi[j];
        #pragma unroll
        for (int c = 0; c < 16; ++c) {
            float4 w4 = wr[c];
            float4 x4 = reinterpret_cast<const float4*>(xs)[c];
            acc += x4.x*w4.x + x4.y*w4.y + x4.z*w4.z + x4.w*w4.w;
        }
        out[n*512 + j] = acc;
    }
}

// ---------------- fused bias path: bias_p GEMM + diffs + bias_out GEMM+mish ----------------
__global__ __launch_bounds__(256, 2) void bias_kernel(
    const float* __restrict__ bias, const unsigned short* __restrict__ wb_bf,
    const float* __restrict__ bb, const unsigned short* __restrict__ wbo_bf,
    const float* __restrict__ bbo, float* __restrict__ bias_out,
    float* __restrict__ diffs)
{
    __shared__ unsigned short lA[64*LDK];    // bias tile bf16
    __shared__ unsigned short lW[128*LDK];   // weight chunk bf16 (Wb_h then Wbo_h)
    __shared__ unsigned short lP[64*LDK];    // bias_p chunk bf16
    __shared__ float sq[64];

    const int tid  = threadIdx.x;
    const int wave = tid >> 6, lane = tid & 63;
    const int quad = lane >> 4, l16 = lane & 15;
    const long row0 = (long)blockIdx.x * 64;
    const int colb = wave * 32;

    // stage bias tile: 64 rows x 128, fp32 -> bf16
    {
        const float* src = bias + row0 * 128;
        #pragma unroll
        for (int i = 0; i < 8; ++i) {
            int flat = i*1024 + tid*4;
            int r = flat >> 7, c = flat & 127;
            float4 v = *reinterpret_cast<const float4*>(src + flat);
            ushort4 o = { f2bf(v.x), f2bf(v.y), f2bf(v.z), f2bf(v.w) };
            *reinterpret_cast<ushort4*>(&lA[r*LDK + c]) = o;
        }
    }

    floatx4 acc2[4][2];
    #pragma unroll
    for (int mt = 0; mt < 4; ++mt)
        #pragma unroll
        for (int nt = 0; nt < 2; ++nt) acc2[mt][nt] = (floatx4){0.f,0.f,0.f,0.f};

    for (int h = 0; h < 4; ++h) {
        // stage Wb_h chunk [128 n1][128 k] bf16
        #pragma unroll
        for (int i = 0; i < 8; ++i) {
            int flat = i*2048 + tid*8;
            int r = flat >> 7, c = flat & 127;
            *reinterpret_cast<uint4*>(&lW[r*LDK + c]) =
                *reinterpret_cast<const uint4*>(wb_bf + h*16384 + flat);
        }
        if (tid < 64) sq[tid] = 0.f;
        __syncthreads();

        // phase 1: C1 = A @ Wb_h^T  (per wave: 64 rows x 32 cols)
        floatx4 acc1[4][2];
        #pragma unroll
        for (int mt = 0; mt < 4; ++mt)
            #pragma unroll
            for (int nt = 0; nt < 2; ++nt) acc1[mt][nt] = (floatx4){0.f,0.f,0.f,0.f};
        #pragma unroll
        for (int kk = 0; kk < 4; ++kk) {
            short8 a[4], bfr[2];
            #pragma unroll
            for (int mt = 0; mt < 4; ++mt)
                a[mt] = *reinterpret_cast<const short8*>(&lA[(mt*16 + l16)*LDK + kk*32 + quad*8]);
            #pragma unroll
            for (int nt = 0; nt < 2; ++nt)
                bfr[nt] = *reinterpret_cast<const short8*>(&lW[(colb + nt*16 + l16)*LDK + kk*32 + quad*8]);
            #pragma unroll
            for (int mt = 0; mt < 4; ++mt)
                #pragma unroll
                for (int nt = 0; nt < 2; ++nt)
                    acc1[mt][nt] = __builtin_amdgcn_mfma_f32_16x16x32_bf16(a[mt], bfr[nt], acc1[mt][nt], 0, 0, 0);
        }

        // add bb_, accumulate sumsq (for diffs), write P chunk as bf16
        float bbv0 = bb[h*128 + colb + l16];
        float bbv1 = bb[h*128 + colb + 16 + l16];
        #pragma unroll
        for (int mt = 0; mt < 4; ++mt) {
            #pragma unroll
            for (int r = 0; r < 4; ++r) {
                float c0 = acc1[mt][0][r] + bbv0;
                float c1 = acc1[mt][1][r] + bbv1;
                float s = c0*c0 + c1*c1;
                s += __shfl_xor(s, 1);
                s += __shfl_xor(s, 2);
                s += __shfl_xor(s, 4);
                s += __shfl_xor(s, 8);
                int m = mt*16 + quad*4 + r;
                if (l16 == 0) atomicAdd(&sq[m], s);
                lP[m*LDK + colb + l16]      = f2bf(c0);
                lP[m*LDK + colb + 16 + l16] = f2bf(c1);
            }
        }
        __syncthreads();
        if (tid < 64) diffs[(long)h*MROWS + row0 + tid] = sqrtf(sq[tid]);

        // stage Wbo chunk [128 n2][128 k2=h*128..] bf16
        #pragma unroll
        for (int i = 0; i < 8; ++i) {
            int flat = i*2048 + tid*8;
            int r = flat >> 7, c = flat & 127;
            *reinterpret_cast<uint4*>(&lW[r*LDK + c]) =
                *reinterpret_cast<const uint4*>(wbo_bf + r*512 + h*128 + c);
        }
        __syncthreads();

        // phase 2: C2 += P_h @ Wbo_h^T
        #pragma unroll
        for (int kk = 0; kk < 4; ++kk) {
            short8 a[4], bfr[2];
            #pragma unroll
            for (int mt = 0; mt < 4; ++mt)
                a[mt] = *reinterpret_cast<const short8*>(&lP[(mt*16 + l16)*LDK + kk*32 + quad*8]);
            #pragma unroll
            for (int nt = 0; nt < 2; ++nt)
                bfr[nt] = *reinterpret_cast<const short8*>(&lW[(colb + nt*16 + l16)*LDK + kk*32 + quad*8]);
            #pragma unroll
            for (int mt = 0; mt < 4; ++mt)
                #pragma unroll
                for (int nt = 0; nt < 2; ++nt)
                    acc2[mt][nt] = __builtin_amdgcn_mfma_f32_16x16x32_bf16(a[mt], bfr[nt], acc2[mt][nt], 0, 0, 0);
        }
        __syncthreads();
    }

    // epilogue: bias_out = mish(C2 + bbo)
    #pragma unroll
    for (int nt = 0; nt < 2; ++nt) {
        int n2 = colb + nt*16 + l16;
        float bv = bbo[n2];
        #pragma unroll
        for (int mt = 0; mt < 4; ++mt) {
            #pragma unroll
            for (int r = 0; r < 4; ++r) {
                int m = mt*16 + quad*4 + r;
                float s = acc2[mt][nt][r] + bv;
                float e = __expf(s);
                float u = 1.f + e, u2 = u*u;
                float msh = (s > 15.f) ? s : s * (u2 - 1.f) / (u2 + 1.f);
                bias_out[(row0 + m)*128 + n2] = msh;
            }
        }
    }
}

// ---------------- QK^T logits (in-place over diffs): logits = pq.pk/sqrt(D) + diffs ----------------
__global__ __launch_bounds__(256) void qk_kernel(
    const float* __restrict__ pq, const float* __restrict__ pk,
    float* __restrict__ logits)
{
    __shared__ float A[64*128];
    __shared__ float BT[128*64];
    int blk = blockIdx.x;
    int kt = blk & 7, h = (blk >> 3) & 3, qt = blk >> 5;
    int tid = threadIdx.x;

    #pragma unroll
    for (int i = 0; i < 8; ++i) {
        int flat = i*1024 + tid*4;
        int r = flat >> 7, c = flat & 127;
        *reinterpret_cast<float4*>(&A[flat]) =
            *reinterpret_cast<const float4*>(pq + (size_t)(qt*64 + r)*512 + h*128 + c);
    }
    {
        int kk = tid & 63, g = tid >> 6;
        #pragma unroll
        for (int i = 0; i < 8; ++i) {
            int d0 = g*32 + i*4;
            float4 vv = *reinterpret_cast<const float4*>(pk + (size_t)(kt*64 + kk)*512 + h*128 + d0);
            BT[(d0+0)*64 + kk] = vv.x;
            BT[(d0+1)*64 + kk] = vv.y;
            BT[(d0+2)*64 + kk] = vv.z;
            BT[(d0+3)*64 + kk] = vv.w;
        }
    }
    __syncthreads();

    int qg = tid >> 4, kg = tid & 15;
    int qs = qg*4, ks = kg*4;
    float acc[4][4] = {};
    for (int d = 0; d < 128; d += 4) {
        float a_[4][4], b_[4][4];
        #pragma unroll
        for (int i = 0; i < 4; ++i) {
            float4 av = *reinterpret_cast<const float4*>(&A[(qs+i)*128 + d]);
            a_[i][0] = av.x; a_[i][1] = av.y; a_[i][2] = av.z; a_[i][3] = av.w;
        }
        #pragma unroll
        for (int dd = 0; dd < 4; ++dd) {
            float4 bv = *reinterpret_cast<const float4*>(&BT[(d+dd)*64 + ks]);
            b_[dd][0] = bv.x; b_[dd][1] = bv.y; b_[dd][2] = bv.z; b_[dd][3] = bv.w;
        }
        #pragma unroll
        for (int i = 0; i < 4; ++i)
            #pragma unroll
            for (int j = 0; j < 4; ++j)
                acc[i][j] += a_[i][0]*b_[0][j] + a_[i][1]*b_[1][j]
                           + a_[i][2]*b_[2][j] + a_[i][3]*b_[3][j];
    }

    const float scale = 0.088388347648318447f;   // 1/sqrt(128)
    #pragma unroll
    for (int i = 0; i < 4; ++i) {
        size_t off = (size_t)h*MROWS + (size_t)(qt*64 + qs + i)*512 + kt*64 + ks;
        float4* p = reinterpret_cast<float4*>(logits + off);
        float4 dv = *p;
        dv.x = fmaf(acc[i][0], scale, dv.x);
        dv.y = fmaf(acc[i][1], scale, dv.y);
        dv.z = fmaf(acc[i][2], scale, dv.z);
        dv.w = fmaf(acc[i][3], scale, dv.w);
        *p = dv;
    }
}

// ---------------- softmax + v reduction -> vals_mean ----------------
__global__ __launch_bounds__(256) void attnval_kernel(
    const float* __restrict__ logits, const float* __restrict__ v,
    float* __restrict__ vmean)
{
    __shared__ float red[32];
    int qrow = blockIdx.x, tid = threadIdx.x;
    int wid = tid >> 6;
    float vsum = 0.f;
    float v0 = v[tid], v1 = v[tid + 256];
    for (int h = 0; h < 4; ++h) {
        const float* lr = logits + (size_t)h*MROWS + (size_t)qrow*512;
        float l0 = lr[tid], l1 = lr[tid + 256];
        float m = fmaxf(l0, l1);
        #pragma unroll
        for (int o = 1; o < 64; o <<= 1) m = fmaxf(m, __shfl_xor(m, o));
        if ((tid & 63) == 0) red[wid] = m;
        __syncthreads();
        m = fmaxf(fmaxf(red[0], red[1]), fmaxf(red[2], red[3]));
        float e0 = __expf(l0 - m), e1 = __expf(l1 - m);
        float s = e0 + e1;
        float sv = e0*v0 + e1*v1;
        #pragma unroll
        for (int o = 1; o < 64; o <<= 1) { s += __shfl_xor(s, o); sv += __shfl_xor(sv, o); }
        __syncthreads();
        if ((tid & 63) == 0) { red[8 + wid] = s; red[16 + wid] = sv; }
        __syncthreads();
        float S  = red[8]  + red[9]  + red[10] + red[11];
        float SV = red[16] + red[17] + red[18] + red[19];
        vsum += SV / S;
        __syncthreads();
    }
    if (tid == 0) vmean[qrow] = vsum * 0.25f;
}

// ---------------- q_new/k_new: layernorm(x + mish(p_flat @ W.T + b)) ----------------
__global__ __launch_bounds__(256) void qkout_kernel(
    const float* __restrict__ p, const float* __restrict__ x,
    const float* __restrict__ W, const float* __restrict__ bo,
    const float* __restrict__ g, const float* __restrict__ be,
    float* __restrict__ out)
{
    __shared__ float pr[512];
    __shared__ float red[256];
    int n = blockIdx.x, tid = threadIdx.x;
    if (tid < 128)
        reinterpret_cast<float4*>(pr)[tid] = reinterpret_cast<const float4*>(p + (size_t)n*512)[tid];
    __syncthreads();
    int o = tid >> 2, part = tid & 3;
    const float4* wr = reinterpret_cast<const float4*>(W + o*512 + part*128);
    float acc = 0.f;
    #pragma unroll
    for (int c = 0; c < 32; ++c) {
        float4 w4 = wr[c];
        int base = part*32 + c;
        acc += pr[base]*w4.x + pr[128 + base]*w4.y + pr[256 + base]*w4.z + pr[384 + base]*w4.w;
    }
    red[tid] = acc;
    __syncthreads();
    if (tid < 64) {
        float s = red[tid*4] + red[tid*4+1] + red[tid*4+2] + red[tid*4+3] + bo[tid];
        float e = __expf(s);
        float u = 1.f + e, u2 = u*u;
        float msh = (s > 15.f) ? s : s * (u2 - 1.f) / (u2 + 1.f);
        float val = x[n*64 + tid] + msh;
        float m = val, m2 = val*val;
        #pragma unroll
        for (int off = 1; off < 64; off <<= 1) { m += __shfl_xor(m, off); m2 += __shfl_xor(m2, off); }
        m *= (1.f/64.f); m2 *= (1.f/64.f);
        float var = m2 - m*m;
        out[n*64 + tid] = (val - m) * rsqrtf(var + 1e-5f) * g[tid] + be[tid];
    }
}

extern "C" void kernel_launch(void* const* d_in, const int* in_sizes, int n_in,
                              void* d_out, int out_size, void* d_ws, size_t ws_size,
                              hipStream_t stream) {
    const float* q    = (const float*)d_in[0];
    const float* k    = (const float*)d_in[1];
    const float* v    = (const float*)d_in[2];
    const float* bias = (const float*)d_in[3];
    const float* Wq   = (const float*)d_in[4];
    const float* bq   = (const float*)d_in[5];
    const float* Wk   = (const float*)d_in[6];
    const float* bk   = (const float*)d_in[7];
    const float* Wqo  = (const float*)d_in[8];
    const float* bqo  = (const float*)d_in[9];
    const float* Wko  = (const float*)d_in[10];
    const float* bko  = (const float*)d_in[11];
    const float* qlg  = (const float*)d_in[12];
    const float* qlb  = (const float*)d_in[13];
    const float* klg  = (const float*)d_in[14];
    const float* klb  = (const float*)d_in[15];
    const float* Wb   = (const float*)d_in[16];
    const float* bb   = (const float*)d_in[17];
    const float* Wbo  = (const float*)d_in[18];
    const float* bbo  = (const float*)d_in[19];

    float* out = (float*)d_out;
    float* ws  = (float*)d_ws;
    float* diffs = ws;                                 // 4*262144 fp32 (also logits, in place)
    float* pq    = ws + 4*MROWS;                       // 262144
    float* pk    = pq + MROWS;                         // 262144
    unsigned short* wbf = (unsigned short*)(pk + MROWS); // 131072 bf16 (Wb | Wbo)

    float* q_new = out;             // 512*64
    float* k_new = out + 32768;     // 512*64
    float* vmean = out + 65536;     // 512
    float* b_out = out + 66048;     // 512*512*128

    prep_kernel<<<dim3(512), dim3(256), 0, stream>>>(Wb, Wbo, wbf);
    proj_kernel<<<dim3(1024), dim3(256), 0, stream>>>(q, k, Wq, bq, Wk, bk, pq, pk);
    bias_kernel<<<dim3(4096), dim3(256), 0, stream>>>(bias, wbf, bb, wbf + 65536, bbo, b_out, diffs);
    qk_kernel<<<dim3(256), dim3(256), 0, stream>>>(pq, pk, diffs);
    attnval_kernel<<<dim3(512), dim3(256), 0, stream>>>(diffs, v, vmean);
    qkout_kernel<<<dim3(512), dim3(256), 0, stream>>>(pq, q, Wqo, bqo, qlg, qlb, q_new);
    qkout_kernel<<<dim3(512), dim3(256), 0, stream>>>(pk, k, Wko, bko, klg, klb, k_new);
}

// Round 2
// 447.395 us; speedup vs baseline: 1.0725x; 1.0725x over previous
//
#include <hip/hip_runtime.h>

#define NN 512
#define MROWS (NN*NN)        // 262144
#define LDK 136              // padded row stride (128 + 8), 16B-aligned rows

typedef __attribute__((ext_vector_type(8))) short short8;
typedef __attribute__((ext_vector_type(16))) float floatx16;

__device__ __forceinline__ unsigned short f2bf(float f) {
    union { float f; unsigned u; } x; x.f = f;
    unsigned r = x.u + 0x7fffu + ((x.u >> 16) & 1u);
    return (unsigned short)(r >> 16);
}

__device__ __forceinline__ floatx16 zero16() {
    floatx16 z;
    #pragma unroll
    for (int i = 0; i < 16; ++i) z[i] = 0.f;
    return z;
}

// ---------------- pre: proj (blocks 0..1023) + weight bf16 convert (1024..1535) ----------------
__global__ __launch_bounds__(256) void pre_kernel(
    const float* __restrict__ q, const float* __restrict__ k,
    const float* __restrict__ Wq, const float* __restrict__ bq,
    const float* __restrict__ Wk, const float* __restrict__ bk,
    float* __restrict__ pq, float* __restrict__ pk,
    const float* __restrict__ Wb, const float* __restrict__ Wbo,
    unsigned short* __restrict__ wbf)
{
    int b = blockIdx.x;
    int tid = threadIdx.x;
    if (b >= 1024) {
        int i = (b - 1024) * 256 + tid;          // 131072 elems
        float v = (i < 65536) ? Wb[i] : Wbo[i - 65536];
        wbf[i] = f2bf(v);
        return;
    }
    __shared__ float xs[64];
    int n = b & 511;
    int is_k = b >> 9;
    const float* x  = is_k ? k  : q;
    const float* W  = is_k ? Wk : Wq;
    const float* bi = is_k ? bk : bq;
    float* out      = is_k ? pk : pq;
    if (tid < 16)
        reinterpret_cast<float4*>(xs)[tid] = reinterpret_cast<const float4*>(x + n*64)[tid];
    __syncthreads();
    #pragma unroll
    for (int jj = 0; jj < 2; ++jj) {
        int j = jj*256 + tid;
        const float4* wr = reinterpret_cast<const float4*>(W + j*64);
        float acc = bi[j];
        #pragma unroll
        for (int c = 0; c < 16; ++c) {
            float4 w4 = wr[c];
            float4 x4 = reinterpret_cast<const float4*>(xs)[c];
            acc += x4.x*w4.x + x4.y*w4.y + x4.z*w4.z + x4.w*w4.w;
        }
        out[n*512 + j] = acc;
    }
}

// ---------------- fused bias path v2: transposed 32x32x16 MFMA, weights from global ----------------
__global__ __launch_bounds__(256, 4) void bias_kernel(
    const float* __restrict__ bias, const unsigned short* __restrict__ wb_bf,
    const float* __restrict__ bb, const unsigned short* __restrict__ wbo_bf,
    const float* __restrict__ bbo, float* __restrict__ bias_out,
    float* __restrict__ diffs)
{
    __shared__ __align__(16) char smem[34816 + 256];
    unsigned short* lA = (unsigned short*)smem;            // [64][LDK] bias tile bf16
    unsigned short* lP = (unsigned short*)(smem + 17408);  // [64][LDK] P chunk bf16
    float* sq = (float*)(smem + 34816);                    // [64]
    float* lT = (float*)smem;                              // [64][LDK] fp32 (epilogue reuse)

    const int tid = threadIdx.x;
    const int w   = tid >> 6;          // wave id -> n1/n2 slice w*32
    const int l   = tid & 63;
    const int l31 = l & 31;
    const int qh  = l >> 5;            // lane half
    const long row0 = (long)blockIdx.x * 64;

    // stage bias tile 64x128 fp32 -> bf16 into lA; zero sq
    {
        const float* src = bias + row0 * 128;
        #pragma unroll
        for (int i = 0; i < 4; ++i) {
            int flat = i*2048 + tid*8;
            int r = flat >> 7, c = flat & 127;
            float4 v0 = *reinterpret_cast<const float4*>(src + flat);
            float4 v1 = *reinterpret_cast<const float4*>(src + flat + 4);
            ushort4 o0 = { f2bf(v0.x), f2bf(v0.y), f2bf(v0.z), f2bf(v0.w) };
            ushort4 o1 = { f2bf(v1.x), f2bf(v1.y), f2bf(v1.z), f2bf(v1.w) };
            *reinterpret_cast<ushort4*>(&lA[r*LDK + c])     = o0;
            *reinterpret_cast<ushort4*>(&lA[r*LDK + c + 4]) = o1;
        }
        if (tid < 64) sq[tid] = 0.f;
    }

    floatx16 acc2[2];
    acc2[0] = zero16(); acc2[1] = zero16();

    // per-lane global weight bases (rows contiguous in k)
    const unsigned short* wbbase  = wb_bf  + (w*32 + l31)*128 + qh*8;   // Wb row n1 (+h*16384 per h)
    const unsigned short* wbobase = wbo_bf + (w*32 + l31)*512 + qh*8;   // Wbo row n2 (+h*128 per h)

    __syncthreads();

    for (int h = 0; h < 4; ++h) {
        // ---- phase 1: C1^T[n1][m] = Wb_h . bias^T ----
        floatx16 acc1[2];
        acc1[0] = zero16(); acc1[1] = zero16();
        const unsigned short* wa = wbbase + h*16384;
        #pragma unroll
        for (int kk = 0; kk < 8; ++kk) {
            short8 afr = *reinterpret_cast<const short8*>(wa + kk*16);
            short8 b0  = *reinterpret_cast<const short8*>(&lA[(l31)*LDK      + kk*16 + qh*8]);
            short8 b1  = *reinterpret_cast<const short8*>(&lA[(32 + l31)*LDK + kk*16 + qh*8]);
            acc1[0] = __builtin_amdgcn_mfma_f32_32x32x16_bf16(afr, b0, acc1[0], 0, 0, 0);
            acc1[1] = __builtin_amdgcn_mfma_f32_32x32x16_bf16(afr, b1, acc1[1], 0, 0, 0);
        }

        // ---- epilogue: +bb, lane-local sumsq, bf16 pack ----
        float4 bbq[4];
        #pragma unroll
        for (int s = 0; s < 4; ++s)
            bbq[s] = *reinterpret_cast<const float4*>(bb + h*128 + w*32 + qh*4 + s*8);

        float ssum[2];
        ushort4 pk4[2][4];
        #pragma unroll
        for (int nt = 0; nt < 2; ++nt) {
            float sa = 0.f;
            #pragma unroll
            for (int s = 0; s < 4; ++s) {
                const float* bbp = (const float*)&bbq[s];
                float v0 = acc1[nt][s*4+0] + bbp[0];
                float v1 = acc1[nt][s*4+1] + bbp[1];
                float v2 = acc1[nt][s*4+2] + bbp[2];
                float v3 = acc1[nt][s*4+3] + bbp[3];
                sa += v0*v0 + v1*v1 + v2*v2 + v3*v3;
                pk4[nt][s] = (ushort4){ f2bf(v0), f2bf(v1), f2bf(v2), f2bf(v3) };
            }
            sa += __shfl_xor(sa, 32);
            ssum[nt] = sa;
        }

        __syncthreads();   // B1: prev phase2 lP reads done; sq zero visible

        #pragma unroll
        for (int nt = 0; nt < 2; ++nt) {
            int m = nt*32 + l31;
            #pragma unroll
            for (int s = 0; s < 4; ++s)
                *reinterpret_cast<ushort4*>(&lP[m*LDK + w*32 + qh*4 + s*8]) = pk4[nt][s];
            if (l < 32) atomicAdd(&sq[m], ssum[nt]);
        }

        __syncthreads();   // B2: lP + sq complete

        if (tid < 64) {
            float s2 = sq[tid];
            diffs[(long)h*MROWS + row0 + tid] = sqrtf(s2);
            sq[tid] = 0.f;                     // ready for next h
        }

        // ---- phase 2: C2^T[n2][m] += Wbo_h . P_h^T ----
        const unsigned short* wo = wbobase + h*128;
        #pragma unroll
        for (int kk = 0; kk < 8; ++kk) {
            short8 afr = *reinterpret_cast<const short8*>(wo + kk*16);
            short8 b0  = *reinterpret_cast<const short8*>(&lP[(l31)*LDK      + kk*16 + qh*8]);
            short8 b1  = *reinterpret_cast<const short8*>(&lP[(32 + l31)*LDK + kk*16 + qh*8]);
            acc2[0] = __builtin_amdgcn_mfma_f32_32x32x16_bf16(afr, b0, acc2[0], 0, 0, 0);
            acc2[1] = __builtin_amdgcn_mfma_f32_32x32x16_bf16(afr, b1, acc2[1], 0, 0, 0);
        }
    }

    // ---- final epilogue: +bbo, mish, transpose via LDS, coalesced float4 stores ----
    float4 bboq[4];
    #pragma unroll
    for (int s = 0; s < 4; ++s)
        bboq[s] = *reinterpret_cast<const float4*>(bbo + w*32 + qh*4 + s*8);

    float outs[2][16];
    #pragma unroll
    for (int nt = 0; nt < 2; ++nt) {
        #pragma unroll
        for (int s = 0; s < 4; ++s) {
            const float* bp = (const float*)&bboq[s];
            #pragma unroll
            for (int r = 0; r < 4; ++r) {
                float x = acc2[nt][s*4+r] + bp[r];
                float e = __expf(x);
                float u = 1.f + e, u2 = u*u;
                outs[nt][s*4+r] = (x > 15.f) ? x : x * (u2 - 1.f) / (u2 + 1.f);
            }
        }
    }

    __syncthreads();   // all lP reads done; smem free for lT
    #pragma unroll
    for (int nt = 0; nt < 2; ++nt) {
        int m = nt*32 + l31;
        #pragma unroll
        for (int s = 0; s < 4; ++s)
            #pragma unroll
            for (int r = 0; r < 4; ++r)
                lT[m*LDK + w*32 + qh*4 + s*8 + r] = outs[nt][s*4+r];
    }
    __syncthreads();
    #pragma unroll
    for (int i = 0; i < 8; ++i) {
        int flat = i*1024 + tid*4;
        int r = flat >> 7, c = flat & 127;
        *reinterpret_cast<float4*>(bias_out + (row0 + r)*128 + c) =
            *reinterpret_cast<const float4*>(&lT[r*LDK + c]);
    }
}

// ---------------- QK^T logits (in-place over diffs): logits = pq.pk/sqrt(D) + diffs ----------------
__global__ __launch_bounds__(256) void qk_kernel(
    const float* __restrict__ pq, const float* __restrict__ pk,
    float* __restrict__ logits)
{
    __shared__ float A[64*128];
    __shared__ float BT[128*64];
    int blk = blockIdx.x;
    int kt = blk & 7, h = (blk >> 3) & 3, qt = blk >> 5;
    int tid = threadIdx.x;

    #pragma unroll
    for (int i = 0; i < 8; ++i) {
        int flat = i*1024 + tid*4;
        int r = flat >> 7, c = flat & 127;
        *reinterpret_cast<float4*>(&A[flat]) =
            *reinterpret_cast<const float4*>(pq + (size_t)(qt*64 + r)*512 + h*128 + c);
    }
    {
        int kk = tid & 63, g = tid >> 6;
        #pragma unroll
        for (int i = 0; i < 8; ++i) {
            int d0 = g*32 + i*4;
            float4 vv = *reinterpret_cast<const float4*>(pk + (size_t)(kt*64 + kk)*512 + h*128 + d0);
            BT[(d0+0)*64 + kk] = vv.x;
            BT[(d0+1)*64 + kk] = vv.y;
            BT[(d0+2)*64 + kk] = vv.z;
            BT[(d0+3)*64 + kk] = vv.w;
        }
    }
    __syncthreads();

    int qg = tid >> 4, kg = tid & 15;
    int qs = qg*4, ks = kg*4;
    float acc[4][4] = {};
    for (int d = 0; d < 128; d += 4) {
        float a_[4][4], b_[4][4];
        #pragma unroll
        for (int i = 0; i < 4; ++i) {
            float4 av = *reinterpret_cast<const float4*>(&A[(qs+i)*128 + d]);
            a_[i][0] = av.x; a_[i][1] = av.y; a_[i][2] = av.z; a_[i][3] = av.w;
        }
        #pragma unroll
        for (int dd = 0; dd < 4; ++dd) {
            float4 bv = *reinterpret_cast<const float4*>(&BT[(d+dd)*64 + ks]);
            b_[dd][0] = bv.x; b_[dd][1] = bv.y; b_[dd][2] = bv.z; b_[dd][3] = bv.w;
        }
        #pragma unroll
        for (int i = 0; i < 4; ++i)
            #pragma unroll
            for (int j = 0; j < 4; ++j)
                acc[i][j] += a_[i][0]*b_[0][j] + a_[i][1]*b_[1][j]
                           + a_[i][2]*b_[2][j] + a_[i][3]*b_[3][j];
    }

    const float scale = 0.088388347648318447f;   // 1/sqrt(128)
    #pragma unroll
    for (int i = 0; i < 4; ++i) {
        size_t off = (size_t)h*MROWS + (size_t)(qt*64 + qs + i)*512 + kt*64 + ks;
        float4* p = reinterpret_cast<float4*>(logits + off);
        float4 dv = *p;
        dv.x = fmaf(acc[i][0], scale, dv.x);
        dv.y = fmaf(acc[i][1], scale, dv.y);
        dv.z = fmaf(acc[i][2], scale, dv.z);
        dv.w = fmaf(acc[i][3], scale, dv.w);
        *p = dv;
    }
}

// ---------------- softmax + v reduction -> vals_mean ----------------
__global__ __launch_bounds__(256) void attnval_kernel(
    const float* __restrict__ logits, const float* __restrict__ v,
    float* __restrict__ vmean)
{
    __shared__ float red[32];
    int qrow = blockIdx.x, tid = threadIdx.x;
    int wid = tid >> 6;
    float vsum = 0.f;
    float v0 = v[tid], v1 = v[tid + 256];
    for (int h = 0; h < 4; ++h) {
        const float* lr = logits + (size_t)h*MROWS + (size_t)qrow*512;
        float l0 = lr[tid], l1 = lr[tid + 256];
        float m = fmaxf(l0, l1);
        #pragma unroll
        for (int o = 1; o < 64; o <<= 1) m = fmaxf(m, __shfl_xor(m, o));
        if ((tid & 63) == 0) red[wid] = m;
        __syncthreads();
        m = fmaxf(fmaxf(red[0], red[1]), fmaxf(red[2], red[3]));
        float e0 = __expf(l0 - m), e1 = __expf(l1 - m);
        float s = e0 + e1;
        float sv = e0*v0 + e1*v1;
        #pragma unroll
        for (int o = 1; o < 64; o <<= 1) { s += __shfl_xor(s, o); sv += __shfl_xor(sv, o); }
        __syncthreads();
        if ((tid & 63) == 0) { red[8 + wid] = s; red[16 + wid] = sv; }
        __syncthreads();
        float S  = red[8]  + red[9]  + red[10] + red[11];
        float SV = red[16] + red[17] + red[18] + red[19];
        vsum += SV / S;
        __syncthreads();
    }
    if (tid == 0) vmean[qrow] = vsum * 0.25f;
}

// ---------------- q_new/k_new: layernorm(x + mish(p_flat @ W.T + b)) ----------------
__global__ __launch_bounds__(256) void qkout_kernel(
    const float* __restrict__ p, const float* __restrict__ x,
    const float* __restrict__ W, const float* __restrict__ bo,
    const float* __restrict__ g, const float* __restrict__ be,
    float* __restrict__ out)
{
    __shared__ float pr[512];
    __shared__ float red[256];
    int n = blockIdx.x, tid = threadIdx.x;
    if (tid < 128)
        reinterpret_cast<float4*>(pr)[tid] = reinterpret_cast<const float4*>(p + (size_t)n*512)[tid];
    __syncthreads();
    int o = tid >> 2, part = tid & 3;
    const float4* wr = reinterpret_cast<const float4*>(W + o*512 + part*128);
    float acc = 0.f;
    #pragma unroll
    for (int c = 0; c < 32; ++c) {
        float4 w4 = wr[c];
        int base = part*32 + c;
        acc += pr[base]*w4.x + pr[128 + base]*w4.y + pr[256 + base]*w4.z + pr[384 + base]*w4.w;
    }
    red[tid] = acc;
    __syncthreads();
    if (tid < 64) {
        float s = red[tid*4] + red[tid*4+1] + red[tid*4+2] + red[tid*4+3] + bo[tid];
        float e = __expf(s);
        float u = 1.f + e, u2 = u*u;
        float msh = (s > 15.f) ? s : s * (u2 - 1.f) / (u2 + 1.f);
        float val = x[n*64 + tid] + msh;
        float m = val, m2 = val*val;
        #pragma unroll
        for (int off = 1; off < 64; off <<= 1) { m += __shfl_xor(m, off); m2 += __shfl_xor(m2, off); }
        m *= (1.f/64.f); m2 *= (1.f/64.f);
        float var = m2 - m*m;
        out[n*64 + tid] = (val - m) * rsqrtf(var + 1e-5f) * g[tid] + be[tid];
    }
}

extern "C" void kernel_launch(void* const* d_in, const int* in_sizes, int n_in,
                              void* d_out, int out_size, void* d_ws, size_t ws_size,
                              hipStream_t stream) {
    const float* q    = (const float*)d_in[0];
    const float* k    = (const float*)d_in[1];
    const float* v    = (const float*)d_in[2];
    const float* bias = (const float*)d_in[3];
    const float* Wq   = (const float*)d_in[4];
    const float* bq   = (const float*)d_in[5];
    const float* Wk   = (const float*)d_in[6];
    const float* bk   = (const float*)d_in[7];
    const float* Wqo  = (const float*)d_in[8];
    const float* bqo  = (const float*)d_in[9];
    const float* Wko  = (const float*)d_in[10];
    const float* bko  = (const float*)d_in[11];
    const float* qlg  = (const float*)d_in[12];
    const float* qlb  = (const float*)d_in[13];
    const float* klg  = (const float*)d_in[14];
    const float* klb  = (const float*)d_in[15];
    const float* Wb   = (const float*)d_in[16];
    const float* bb   = (const float*)d_in[17];
    const float* Wbo  = (const float*)d_in[18];
    const float* bbo  = (const float*)d_in[19];

    float* out = (float*)d_out;
    float* ws  = (float*)d_ws;
    float* diffs = ws;                                   // 4*262144 fp32 (also logits, in place)
    float* pq    = ws + 4*MROWS;                         // 262144
    float* pk    = pq + MROWS;                           // 262144
    unsigned short* wbf = (unsigned short*)(pk + MROWS); // 131072 bf16 (Wb | Wbo)

    float* q_new = out;             // 512*64
    float* k_new = out + 32768;     // 512*64
    float* vmean = out + 65536;     // 512
    float* b_out = out + 66048;     // 512*512*128

    pre_kernel<<<dim3(1536), dim3(256), 0, stream>>>(q, k, Wq, bq, Wk, bk, pq, pk, Wb, Wbo, wbf);
    bias_kernel<<<dim3(4096), dim3(256), 0, stream>>>(bias, wbf, bb, wbf + 65536, bbo, b_out, diffs);
    qk_kernel<<<dim3(256), dim3(256), 0, stream>>>(pq, pk, diffs);
    attnval_kernel<<<dim3(512), dim3(256), 0, stream>>>(diffs, v, vmean);
    qkout_kernel<<<dim3(512), dim3(256), 0, stream>>>(pq, q, Wqo, bqo, qlg, qlb, q_new);
    qkout_kernel<<<dim3(512), dim3(256), 0, stream>>>(pk, k, Wko, bko, klg, klb, k_new);
}